// Round 2
// baseline (836.504 us; speedup 1.0000x reference)
//
#include <hip/hip_runtime.h>

#define NN 50000
#define NE 600000
#define DD 128
#define HD 512
#define NB 196  // (NN+255)/256 scan blocks

typedef unsigned short u16;
typedef __attribute__((ext_vector_type(8))) short short8;
typedef __attribute__((ext_vector_type(4))) float floatx4;

__device__ inline float b2f(u16 u) {
  return __uint_as_float(((unsigned int)u) << 16);
}
__device__ inline u16 f2b(float f) {
  unsigned int u = __float_as_uint(f);
  u = u + 0x7FFFu + ((u >> 16) & 1u);   // round-to-nearest-even
  return (u16)(u >> 16);
}

// async 16B global->LDS DMA (gfx950). LDS dest = wave-uniform base + lane*16.
__device__ inline void load_lds16(const u16* g, u16* l) {
  __builtin_amdgcn_global_load_lds(
      (const __attribute__((address_space(1))) unsigned int*)(uintptr_t)g,
      (__attribute__((address_space(3))) unsigned int*)(uintptr_t)l,
      16, 0, 0);
}

__global__ void zero_k(int* __restrict__ p, int n) {
  int i = blockIdx.x * 256 + threadIdx.x;
  if (i < n) p[i] = 0;
}

// ---------------- W transpose + fp32->bf16: W[K,512] f32 -> Wt[512,K] bf16 ----
__global__ void transpose_k(const float* __restrict__ W, u16* __restrict__ Wt, int K) {
  int idx = blockIdx.x * 256 + threadIdx.x;
  if (idx >= K * 512) return;
  int k = idx >> 9, n = idx & 511;
  Wt[n * K + k] = f2b(W[idx]);
}

// ---------------- CSR build (multi-block scan) ----------------
__global__ void count_k(const int* __restrict__ dst, int* __restrict__ counts) {
  int e = blockIdx.x * 256 + threadIdx.x;
  if (e < NE) atomicAdd(&counts[dst[e]], 1);
}

__global__ __launch_bounds__(256) void blockscan_k(const int* __restrict__ counts,
                                                   int* __restrict__ rowp,
                                                   int* __restrict__ bsums) {
  __shared__ int tmp[256];
  int t = threadIdx.x;
  int i = blockIdx.x * 256 + t;
  int v = (i < NN) ? counts[i] : 0;
  tmp[t] = v;
  __syncthreads();
  for (int off = 1; off < 256; off <<= 1) {
    int u = (t >= off) ? tmp[t - off] : 0;
    __syncthreads();
    tmp[t] += u;
    __syncthreads();
  }
  if (i < NN) rowp[i] = tmp[t] - v;   // block-local exclusive
  if (t == 255) bsums[blockIdx.x] = tmp[t];
}

__global__ __launch_bounds__(256) void bscan_k(const int* __restrict__ bsums,
                                               int* __restrict__ boffs) {
  __shared__ int tmp[256];
  int t = threadIdx.x;
  int v = (t < NB) ? bsums[t] : 0;
  tmp[t] = v;
  __syncthreads();
  for (int off = 1; off < 256; off <<= 1) {
    int u = (t >= off) ? tmp[t - off] : 0;
    __syncthreads();
    tmp[t] += u;
    __syncthreads();
  }
  if (t < NB) boffs[t] = tmp[t] - v;
}

__global__ void addoff_k(int* __restrict__ rowp, int* __restrict__ cursor,
                         const int* __restrict__ boffs) {
  int i = blockIdx.x * 256 + threadIdx.x;
  if (i < NN) {
    int v = rowp[i] + boffs[blockIdx.x];
    rowp[i] = v;
    cursor[i] = v;
  }
  if (i == 0) rowp[NN] = NE;
}

__global__ void scatter_k(const int* __restrict__ src, const int* __restrict__ dst,
                          int* __restrict__ cursor, int* __restrict__ csrs) {
  int e = blockIdx.x * 256 + threadIdx.x;
  if (e < NE) {
    int d = dst[e];
    int pos = atomicAdd(&cursor[d], 1);
    csrs[pos] = src[e];
  }
}

// ---------------- GEMM + el/er epilogue (async-staged, swizzled LDS) --------
// A[M,K] row-major (fp32 if A_F32 else bf16), Wt[512,K] bf16 pre-transposed.
// Block: 64 rows x 512 cols, 512 threads = 8 waves:
// wave w -> row-group rg=w>>1 (16 rows), col-group cg=w&1 (256 cols).
// B-tile staged via global_load_lds width=16 (async DMA, no VGPR roundtrip).
// LDS layout: row r (0..511) at r*64B, pad-free (DMA needs contiguity); its
// four 16B k-chunks are XOR-swizzled: position p holds source chunk p^((r>>1)&3)
// -> ds_read_b128 per 8-lane group covers all 32 banks (2-way max = free).
// Outputs: h bf16 [N,512], el/er fp32 [N,4] from fp32 accumulators.
template <int K, bool A_F32>
__global__ __launch_bounds__(512) void gemm_el_er(
    const void* __restrict__ Ap, const u16* __restrict__ Wt,
    const float* __restrict__ al, const float* __restrict__ ar,
    u16* __restrict__ h, float* __restrict__ el, float* __restrict__ er) {
  __shared__ u16 Wt_s[512 * 32];   // 32 KB

  const int tid = threadIdx.x;
  const int w = tid >> 6, lane = tid & 63, quad = lane >> 4, l16 = lane & 15;
  const int rg = w >> 1, cg = w & 1;
  const int bm = blockIdx.x;

  floatx4 acc[16] = {};

  const int rowA = bm * 64 + rg * 16 + l16;
  const long arow = (rowA < NN) ? rowA : (NN - 1);

  // staging: lane covers LDS linear [wave_base + lane*16B]; that is row
  // r = rbase + (lane>>2), position p = lane&3, source chunk q = p ^ swz(r).
  // swz(r) = (r>>1)&3 reduces to (lane>>3)&3 since rbase % 16 == 0.
  const int drow = lane >> 2;
  const int q8 = ((lane & 3) ^ ((lane >> 3) & 3)) * 8;   // u16 offset in source
  // read: frag (ct,l16) is row r=cg*256+ct*16+l16; need chunk quad at position
  // quad ^ swz(r); swz(r) = (l16>>1)&3 (ct,cg terms vanish mod 4).
  const int p4 = (quad ^ ((l16 >> 1) & 3)) * 8;          // u16 offset in LDS row

  for (int k0 = 0; k0 < K; k0 += 32) {
#pragma unroll
    for (int rr = 0; rr < 4; ++rr) {
      const int rbase = rr * 128 + w * 16;
      load_lds16(Wt + (long)(rbase + drow) * K + k0 + q8, Wt_s + rbase * 32);
    }
    short8 af;
    if (A_F32) {
      const float* Af = (const float*)Ap;
      floatx4 v0 = *(const floatx4*)(Af + arow * K + k0 + quad * 8);
      floatx4 v1 = *(const floatx4*)(Af + arow * K + k0 + quad * 8 + 4);
      u16 tmp[8];
#pragma unroll
      for (int j = 0; j < 4; ++j) tmp[j] = f2b(v0[j]);
#pragma unroll
      for (int j = 0; j < 4; ++j) tmp[4 + j] = f2b(v1[j]);
      af = *(short8*)tmp;
    } else {
      af = *(const short8*)((const u16*)Ap + arow * K + k0 + quad * 8);
    }
    __syncthreads();   // drains DMA (vmcnt) for all waves
#pragma unroll
    for (int ct = 0; ct < 16; ++ct) {
      short8 bf = *(const short8*)(Wt_s + (cg * 256 + ct * 16 + l16) * 32 + p4);
      acc[ct] = __builtin_amdgcn_mfma_f32_16x16x32_bf16(af, bf, acc[ct], 0, 0, 0);
    }
    __syncthreads();   // reads done before next chunk's DMA overwrites
  }

  float alv[16], arv[16];
#pragma unroll
  for (int ct = 0; ct < 16; ++ct) {
    int col = cg * 256 + ct * 16 + l16;
    alv[ct] = al[col];
    arv[ct] = ar[col];
  }
#pragma unroll
  for (int reg = 0; reg < 4; ++reg) {
    const int r = bm * 64 + rg * 16 + quad * 4 + reg;
    float pel[2] = {0.f, 0.f}, per_[2] = {0.f, 0.f};
#pragma unroll
    for (int ct = 0; ct < 16; ++ct) {
      int hh = ct >> 3;   // head within this col-group (2 heads per cg)
      float v = acc[ct][reg];
      pel[hh] += v * alv[ct];
      per_[hh] += v * arv[ct];
    }
#pragma unroll
    for (int m = 1; m < 16; m <<= 1) {
      pel[0] += __shfl_xor(pel[0], m, 64);
      pel[1] += __shfl_xor(pel[1], m, 64);
      per_[0] += __shfl_xor(per_[0], m, 64);
      per_[1] += __shfl_xor(per_[1], m, 64);
    }
    if (r < NN) {
#pragma unroll
      for (int ct = 0; ct < 16; ++ct)
        h[(long)r * HD + cg * 256 + ct * 16 + l16] = f2b(acc[ct][reg]);
      if (l16 == 0) {
        el[r * 4 + cg * 2] = pel[0];
        el[r * 4 + cg * 2 + 1] = pel[1];
        er[r * 4 + cg * 2] = per_[0];
        er[r * 4 + cg * 2 + 1] = per_[1];
      }
    }
  }
}

// ------------- XCD-column-partitioned edge-softmax + aggregation -------------
// R1 post-mortem: FETCH=303MB per aggregate == per-XCD COMPULSORY traffic
// (each XCD touched ~39K unique 1KB h-rows; L2 already captured all temporal
// reuse). Fix: partition h COLUMNS across XCDs. 16 chunks x 32 cols (64B/edge
// = 1 cache line). Block b -> chunk (b%8) (+8 in the 2nd grid half); the
// blockIdx%8 -> XCD round-robin pins each chunk's 3.2MB column stripe into ONE
// XCD's 4MB L2 -> per-XCD h misses drop to ~3.2MB compulsory. Chunks c and c+8
// share an XCD but run in separate grid halves (dispatch is ~in-order), so
// their stripes don't thrash. Edge metadata (csrs nt-load, el gather, exp) is
// recomputed per chunk: lane-parallel, ~0.4 VALU/edge, and el (800KB) is
// L2-resident.
//   Pass 1 (per 64-edge chunk): lane=edge; w=exp(lrelu(el[src]+er[dst])) for
//     THIS chunk's head only; w,idx -> LDS; sm accumulated lane-parallel.
//   Pass 2: 16 edges/iter = 4 wave-loads; lane (eg,cl) reads 4B (2 bf16) of
//     edge i+4u+eg at cols chunk*32+cl*2; idx/w via conflict-free 16-lane LDS
//     broadcast. Tail slots padded (w=0, idx=last) -> pad loads are L1 hits.
//   Reduce across eg groups (shfl_xor 16,32), butterfly sm, normalize+relu.
// MODE 0: bf16 rst slice [n, chunk*32..+32]. MODE 1: head-mean via f32
// atomicAdd into pre-zeroed out (4 head-chunks contribute to the same d-slice
// from different XCDs; device-scope atomics).
// Grid: 16 chunks x 3125 nodeblocks = 50000 blocks; 4 waves x 4 nodes each.
template <int MODE>
__global__ __launch_bounds__(256) void aggregate_chunk(
    const u16* __restrict__ h, const float* __restrict__ el,
    const float* __restrict__ er, const int* __restrict__ rowp,
    const int* __restrict__ csrs, u16* __restrict__ ob, float* __restrict__ of) {
  __shared__ float w_s[4][64];
  __shared__ int is_s[4][64];
  const int b = blockIdx.x;
  const int half = b / 25000;                 // 0: chunks 0-7, 1: chunks 8-15
  const int chunk = (b & 7) + half * 8;       // chunk % 8 == b % 8 -> XCD-affine
  const int nodeblk = (b % 25000) >> 3;       // 0..3124
  const int wv = threadIdx.x >> 6, lane = threadIdx.x & 63;
  const int hc = chunk >> 2;                  // head of this chunk
  const int eg = lane >> 4, cl = lane & 15;
  const long coff = chunk * 32 + cl * 2;      // u16 offset within h row

  for (int k = 0; k < 4; ++k) {
    const int n = nodeblk * 16 + wv * 4 + k;  // < 50000 by construction
    const int base = rowp[n];
    const int deg = rowp[n + 1] - base;
    if (deg == 0) {  // empty segment: rst row = 0 -> relu -> 0 (out pre-zeroed)
      if (MODE == 0 && lane < 16)
        __builtin_nontemporal_store(0u, (unsigned*)(ob + (long)n * HD + coff));
      continue;
    }
    const float er_h = er[n * 4 + hc];
    float acc0 = 0.f, acc1 = 0.f, sm = 0.f;
    for (int c0 = 0; c0 < deg; c0 += 64) {
      // ---- pass 1: lane-parallel edge metadata (this chunk's head only) ----
      const int l = c0 + lane;
      const int idx =
          __builtin_nontemporal_load(csrs + base + ((l < deg) ? l : (deg - 1)));
      float e = el[idx * 4 + hc] + er_h;
      e = (e > 0.f) ? e : 0.2f * e;
      const float w = (l < deg) ? __expf(e) : 0.f;
      sm += w;
      w_s[wv][lane] = w;
      is_s[wv][lane] = idx;
      // same-wave LDS RAW: compiler inserts lgkmcnt wait, no barrier needed.
      const int cnt = (deg - c0 < 64) ? (deg - c0) : 64;
      // ---- pass 2: 16 edges / iter, 4 independent 256B wave-loads ----
      for (int i = 0; i < cnt; i += 16) {
        int s4[4];
        float wt[4];
        unsigned v4[4];
#pragma unroll
        for (int u = 0; u < 4; ++u) {
          s4[u] = is_s[wv][i + u * 4 + eg];
          wt[u] = w_s[wv][i + u * 4 + eg];
        }
#pragma unroll
        for (int u = 0; u < 4; ++u)
          v4[u] = *(const unsigned*)(h + (long)s4[u] * HD + coff);
#pragma unroll
        for (int u = 0; u < 4; ++u) {
          acc0 += wt[u] * __uint_as_float(v4[u] << 16);
          acc1 += wt[u] * __uint_as_float(v4[u] & 0xFFFF0000u);
        }
      }
    }
    // combine the 4 edge-phase groups (lane bits 4,5)
    acc0 += __shfl_xor(acc0, 16, 64);
    acc0 += __shfl_xor(acc0, 32, 64);
    acc1 += __shfl_xor(acc1, 16, 64);
    acc1 += __shfl_xor(acc1, 32, 64);
#pragma unroll
    for (int m = 1; m < 64; m <<= 1) sm += __shfl_xor(sm, m, 64);
    const float inv = 1.f / sm;
    const float v0 = fmaxf(acc0 * inv, 0.f);
    const float v1 = fmaxf(acc1 * inv, 0.f);
    if (MODE == 0) {
      if (lane < 16) {
        unsigned u = (unsigned)f2b(v0) | ((unsigned)f2b(v1) << 16);
        __builtin_nontemporal_store(u, (unsigned*)(ob + (long)n * HD + coff));
      }
    } else {
      if (lane < 16) {
        float* o = of + (long)n * DD + (chunk & 3) * 32 + cl * 2;
        atomicAdd(o, v0 * 0.25f);
        atomicAdd(o + 1, v1 * 0.25f);
      }
    }
  }
}

extern "C" void kernel_launch(void* const* d_in, const int* in_sizes, int n_in,
                              void* d_out, int out_size, void* d_ws, size_t ws_size,
                              hipStream_t stream) {
  const float* x = (const float*)d_in[0];
  const int* src = (const int*)d_in[1];
  const int* dst = (const int*)d_in[2];
  const float* W0 = (const float*)d_in[3];
  const float* al0 = (const float*)d_in[4];
  const float* ar0 = (const float*)d_in[5];
  const float* W1 = (const float*)d_in[6];
  const float* al1 = (const float*)d_in[7];
  const float* ar1 = (const float*)d_in[8];
  float* out = (float*)d_out;

  char* p = (char*)d_ws;
  u16* h = (u16*)p;        p += (size_t)NN * HD * 2;   // 51.2 MB (bf16)
  u16* rst0 = (u16*)p;     p += (size_t)NN * HD * 2;   // 51.2 MB
  float* el = (float*)p;   p += (size_t)NN * 4 * 4;
  float* er = (float*)p;   p += (size_t)NN * 4 * 4;
  u16* Wt0 = (u16*)p;      p += 512 * 256 * 2;
  u16* Wt1 = (u16*)p;      p += 512 * 512 * 2;
  int* counts = (int*)p;   p += (size_t)NN * 4;
  int* cursor = (int*)p;   p += (size_t)NN * 4;
  int* rowp = (int*)p;     p += (size_t)(NN + 1) * 4;
  int* bsums = (int*)p;    p += 256 * 4;
  int* boffs = (int*)p;    p += 256 * 4;
  int* csrs = (int*)p;     p += (size_t)NE * 4;

  zero_k<<<NB, 256, 0, stream>>>(counts, NN);
  count_k<<<(NE + 255) / 256, 256, 0, stream>>>(dst, counts);
  blockscan_k<<<NB, 256, 0, stream>>>(counts, rowp, bsums);
  bscan_k<<<1, 256, 0, stream>>>(bsums, boffs);
  addoff_k<<<NB, 256, 0, stream>>>(rowp, cursor, boffs);
  scatter_k<<<(NE + 255) / 256, 256, 0, stream>>>(src, dst, cursor, csrs);
  transpose_k<<<(256 * 512 + 255) / 256, 256, 0, stream>>>(W0, Wt0, 256);
  transpose_k<<<(512 * 512 + 255) / 256, 256, 0, stream>>>(W1, Wt1, 512);

  const int gblocks = (NN + 63) / 64;  // 782
  const int ablocks = 50000;           // 16 chunks x 3125 node-blocks
  gemm_el_er<256, true><<<gblocks, 512, 0, stream>>>(x, Wt0, al0, ar0, h, el, er);
  aggregate_chunk<0><<<ablocks, 256, 0, stream>>>(h, el, er, rowp, csrs, rst0, nullptr);
  gemm_el_er<512, false><<<gblocks, 512, 0, stream>>>(rst0, Wt1, al1, ar1, h, el, er);
  zero_k<<<(NN * DD + 255) / 256, 256, 0, stream>>>((int*)out, NN * DD);
  aggregate_chunk<1><<<ablocks, 256, 0, stream>>>(h, el, er, rowp, csrs, nullptr, out);
}

// Round 3
// 466.267 us; speedup vs baseline: 1.7940x; 1.7940x over previous
//
#include <hip/hip_runtime.h>

#define NN 50000
#define NE 600000
#define DD 128
#define HD 512
#define NB 196  // (NN+255)/256 scan blocks

typedef unsigned short u16;
typedef __attribute__((ext_vector_type(8))) short short8;
typedef __attribute__((ext_vector_type(4))) float floatx4;

__device__ inline float b2f(u16 u) {
  return __uint_as_float(((unsigned int)u) << 16);
}
__device__ inline u16 f2b(float f) {
  unsigned int u = __float_as_uint(f);
  u = u + 0x7FFFu + ((u >> 16) & 1u);   // round-to-nearest-even
  return (u16)(u >> 16);
}

// async 16B global->LDS DMA (gfx950). LDS dest = wave-uniform base + lane*16.
__device__ inline void load_lds16(const u16* g, u16* l) {
  __builtin_amdgcn_global_load_lds(
      (const __attribute__((address_space(1))) unsigned int*)(uintptr_t)g,
      (__attribute__((address_space(3))) unsigned int*)(uintptr_t)l,
      16, 0, 0);
}

__global__ void zero_k(int* __restrict__ p, int n) {
  int i = blockIdx.x * 256 + threadIdx.x;
  if (i < n) p[i] = 0;
}

// ---------------- W transpose + fp32->bf16: W[K,512] f32 -> Wt[512,K] bf16 ----
__global__ void transpose_k(const float* __restrict__ W, u16* __restrict__ Wt, int K) {
  int idx = blockIdx.x * 256 + threadIdx.x;
  if (idx >= K * 512) return;
  int k = idx >> 9, n = idx & 511;
  Wt[n * K + k] = f2b(W[idx]);
}

// ---------------- CSR build (multi-block scan) ----------------
__global__ void count_k(const int* __restrict__ dst, int* __restrict__ counts) {
  int e = blockIdx.x * 256 + threadIdx.x;
  if (e < NE) atomicAdd(&counts[dst[e]], 1);
}

__global__ __launch_bounds__(256) void blockscan_k(const int* __restrict__ counts,
                                                   int* __restrict__ rowp,
                                                   int* __restrict__ bsums) {
  __shared__ int tmp[256];
  int t = threadIdx.x;
  int i = blockIdx.x * 256 + t;
  int v = (i < NN) ? counts[i] : 0;
  tmp[t] = v;
  __syncthreads();
  for (int off = 1; off < 256; off <<= 1) {
    int u = (t >= off) ? tmp[t - off] : 0;
    __syncthreads();
    tmp[t] += u;
    __syncthreads();
  }
  if (i < NN) rowp[i] = tmp[t] - v;   // block-local exclusive
  if (t == 255) bsums[blockIdx.x] = tmp[t];
}

__global__ __launch_bounds__(256) void bscan_k(const int* __restrict__ bsums,
                                               int* __restrict__ boffs) {
  __shared__ int tmp[256];
  int t = threadIdx.x;
  int v = (t < NB) ? bsums[t] : 0;
  tmp[t] = v;
  __syncthreads();
  for (int off = 1; off < 256; off <<= 1) {
    int u = (t >= off) ? tmp[t - off] : 0;
    __syncthreads();
    tmp[t] += u;
    __syncthreads();
  }
  if (t < NB) boffs[t] = tmp[t] - v;
}

__global__ void addoff_k(int* __restrict__ rowp, int* __restrict__ cursor,
                         const int* __restrict__ boffs) {
  int i = blockIdx.x * 256 + threadIdx.x;
  if (i < NN) {
    int v = rowp[i] + boffs[blockIdx.x];
    rowp[i] = v;
    cursor[i] = v;
  }
  if (i == 0) rowp[NN] = NE;
}

__global__ void scatter_k(const int* __restrict__ src, const int* __restrict__ dst,
                          int* __restrict__ cursor, int* __restrict__ csrs) {
  int e = blockIdx.x * 256 + threadIdx.x;
  if (e < NE) {
    int d = dst[e];
    int pos = atomicAdd(&cursor[d], 1);
    csrs[pos] = src[e];
  }
}

// ---------------- GEMM + el/er epilogue (pipelined double-buffer) -----------
// A[M,K] row-major (fp32 if A_F32 else bf16), Wt[512,K] bf16 pre-transposed.
// Block: 64 rows x 512 cols, 512 threads = 8 waves:
// wave w -> row-group rg=w>>1 (16 rows), col-group cg=w&1 (256 cols).
//
// R2 change: the old loop issued the B-tile DMA then __syncthreads(), which
// drains vmcnt(0) -> every 32-K step paid full staging latency (the classic
// barrier-drain stall, guide S5). Now: 2x32KB LDS double-buffer, A-fragment
// prefetched into registers one step ahead, counted s_waitcnt vmcnt(N) + raw
// s_barrier so the NEXT tile's loads (4 DMA + A) stay in flight across the
// barrier. Steady state per half-step: issue A(t+1)+DMA(t+1) [N vmem ops],
// vmcnt(N) guarantees step-t ops (issued last half-step) are done, barrier,
// MFMA from buf[t&1]. Second barrier fences reads before buf reuse.
// LDS swizzle unchanged: row r at r*64B, chunk p holds source chunk p^((r>>1)&3).
template <int K, bool A_F32>
__global__ __launch_bounds__(512) void gemm_el_er(
    const void* __restrict__ Ap, const u16* __restrict__ Wt,
    const float* __restrict__ al, const float* __restrict__ ar,
    u16* __restrict__ h, float* __restrict__ el, float* __restrict__ er) {
  __shared__ u16 Wt_s[2][512 * 32];   // 2 x 32 KB

  const int tid = threadIdx.x;
  const int w = tid >> 6, lane = tid & 63, quad = lane >> 4, l16 = lane & 15;
  const int rg = w >> 1, cg = w & 1;
  const int bm = blockIdx.x;

  floatx4 acc[16] = {};

  const int rowA = bm * 64 + rg * 16 + l16;
  const long arow = (rowA < NN) ? rowA : (NN - 1);

  const int drow = lane >> 2;
  const int q8 = ((lane & 3) ^ ((lane >> 3) & 3)) * 8;   // u16 offset in source
  const int p4 = (quad ^ ((l16 >> 1) & 3)) * 8;          // u16 offset in LDS row

  const float* Af = (const float*)Ap;
  const u16* Ab = (const u16*)Ap;

#define ISSUE_DMA(kk, sel)                                                  \
  {                                                                         \
    _Pragma("unroll") for (int rr = 0; rr < 4; ++rr) {                      \
      const int rbase = rr * 128 + w * 16;                                  \
      load_lds16(Wt + (long)(rbase + drow) * K + (kk) + q8,                 \
                 &Wt_s[sel][rbase * 32]);                                   \
    }                                                                       \
  }

  // A prefetch registers (two named sets -- rule #20: no runtime indexing)
  floatx4 a0A, a1A, a0B, a1B;
  short8 rawA, rawB;

#define ISSUE_A(kk, a0r, a1r, rawr)                                         \
  {                                                                         \
    if (A_F32) {                                                            \
      a0r = *(const floatx4*)(Af + arow * K + (kk) + quad * 8);             \
      a1r = *(const floatx4*)(Af + arow * K + (kk) + quad * 8 + 4);         \
    } else {                                                                \
      rawr = *(const short8*)(Ab + arow * K + (kk) + quad * 8);             \
    }                                                                       \
  }

#define CVT_A(af, a0r, a1r, rawr)                                           \
  short8 af;                                                                \
  {                                                                         \
    if (A_F32) {                                                            \
      u16 tmp[8];                                                           \
      _Pragma("unroll") for (int j = 0; j < 4; ++j) tmp[j] = f2b(a0r[j]);   \
      _Pragma("unroll") for (int j = 0; j < 4; ++j) tmp[4 + j] = f2b(a1r[j]); \
      af = *(short8*)tmp;                                                   \
    } else {                                                                \
      af = rawr;                                                            \
    }                                                                       \
  }

  // per half-step VMEM ops: 4 DMA + (2 if fp32 else 1) A loads
#define WAIT_PREV()                                                         \
  {                                                                         \
    if (A_F32)                                                              \
      asm volatile("s_waitcnt vmcnt(6)" ::: "memory");                      \
    else                                                                    \
      asm volatile("s_waitcnt vmcnt(5)" ::: "memory");                      \
  }

  const int T = K / 32;   // 8 or 16 (even)

  // prologue: step 0 into set A / buf 0
  ISSUE_A(0, a0A, a1A, rawA);
  ISSUE_DMA(0, 0);

  for (int t = 0; t < T; t += 2) {
    // ---- even half: consume set A / buf0, prefetch t+1 -> set B / buf1 ----
    {
      const int k1 = (t + 1) * 32;   // t+1 <= T-1 always (T even)
      ISSUE_A(k1, a0B, a1B, rawB);
      ISSUE_DMA(k1, 1);
      WAIT_PREV();                        // step-t DMA+A (older) complete
      __builtin_amdgcn_s_barrier();       // buf0 staged by all waves
      CVT_A(af, a0A, a1A, rawA);
#pragma unroll
      for (int ct = 0; ct < 16; ++ct) {
        short8 bf = *(const short8*)(&Wt_s[0][(cg * 256 + ct * 16 + l16) * 32 + p4]);
        acc[ct] = __builtin_amdgcn_mfma_f32_16x16x32_bf16(af, bf, acc[ct], 0, 0, 0);
      }
      __builtin_amdgcn_sched_barrier(0);  // pin ds_read/MFMA before fence
      __builtin_amdgcn_s_barrier();       // buf0 reads done -> reusable
    }
    // ---- odd half: consume set B / buf1, prefetch t+2 -> set A / buf0 ----
    {
      const int t2 = (t + 2 < T) ? t + 2 : T - 1;   // clamped dummy on last
      const int k2 = t2 * 32;
      ISSUE_A(k2, a0A, a1A, rawA);
      ISSUE_DMA(k2, 0);
      WAIT_PREV();
      __builtin_amdgcn_s_barrier();
      CVT_A(af, a0B, a1B, rawB);
#pragma unroll
      for (int ct = 0; ct < 16; ++ct) {
        short8 bf = *(const short8*)(&Wt_s[1][(cg * 256 + ct * 16 + l16) * 32 + p4]);
        acc[ct] = __builtin_amdgcn_mfma_f32_16x16x32_bf16(af, bf, acc[ct], 0, 0, 0);
      }
      __builtin_amdgcn_sched_barrier(0);
      __builtin_amdgcn_s_barrier();
    }
  }

#undef ISSUE_DMA
#undef ISSUE_A
#undef CVT_A
#undef WAIT_PREV

  float alv[16], arv[16];
#pragma unroll
  for (int ct = 0; ct < 16; ++ct) {
    int col = cg * 256 + ct * 16 + l16;
    alv[ct] = al[col];
    arv[ct] = ar[col];
  }
#pragma unroll
  for (int reg = 0; reg < 4; ++reg) {
    const int r = bm * 64 + rg * 16 + quad * 4 + reg;
    float pel[2] = {0.f, 0.f}, per_[2] = {0.f, 0.f};
#pragma unroll
    for (int ct = 0; ct < 16; ++ct) {
      int hh = ct >> 3;   // head within this col-group (2 heads per cg)
      float v = acc[ct][reg];
      pel[hh] += v * alv[ct];
      per_[hh] += v * arv[ct];
    }
#pragma unroll
    for (int m = 1; m < 16; m <<= 1) {
      pel[0] += __shfl_xor(pel[0], m, 64);
      pel[1] += __shfl_xor(pel[1], m, 64);
      per_[0] += __shfl_xor(per_[0], m, 64);
      per_[1] += __shfl_xor(per_[1], m, 64);
    }
    if (r < NN) {
#pragma unroll
      for (int ct = 0; ct < 16; ++ct)
        h[(long)r * HD + cg * 256 + ct * 16 + l16] = f2b(acc[ct][reg]);
      if (l16 == 0) {
        el[r * 4 + cg * 2] = pel[0];
        el[r * 4 + cg * 2 + 1] = pel[1];
        er[r * 4 + cg * 2] = per_[0];
        er[r * 4 + cg * 2 + 1] = per_[1];
      }
    }
  }
}

// ---------------- fused edge-softmax + aggregation (two-phase, pipelined) ----
// One wave per dst node (R1 structure, proven 93 us -- at the per-CU
// outstanding-miss wall: ~300MB compulsory per-XCD fetch, 3.9 TB/s).
// R2's column-partition variant REGRESSED (FETCH 384MB, 16x metadata redo);
// reverted. One fix vs R1: MODE 0's rst0 store is a NORMAL store (it is
// GEMM2's A-input; nt-bypassing L2 cost ~8-13us downstream). nt only for the
// final out (never re-read).
template <int MODE>
__global__ __launch_bounds__(256) void aggregate(
    const u16* __restrict__ h, const float* __restrict__ el,
    const float* __restrict__ er, const int* __restrict__ rowp,
    const int* __restrict__ csrs, u16* __restrict__ ob, float* __restrict__ of) {
  __shared__ float w_s[4][64][4];   // [wave][edge][head], 4 KB
  const int wv = threadIdx.x >> 6, lane = threadIdx.x & 63;
  const int n = blockIdx.x * 4 + wv;
  if (n >= NN) return;
  const int base = rowp[n];
  const int deg = rowp[n + 1] - base;
  const int head = lane >> 4;

  if (deg == 0) {  // empty segment: rst row = 0 -> relu -> 0
    if (MODE == 0) {
      short8 z = {};
      *(short8*)(ob + (long)n * HD + lane * 8) = z;
    } else if (lane < 16) {
      floatx4 z = {};
      __builtin_nontemporal_store(z, (floatx4*)(of + (long)n * DD + lane * 8));
      __builtin_nontemporal_store(z, (floatx4*)(of + (long)n * DD + lane * 8 + 4));
    }
    return;
  }

  const floatx4 er4 = *(const floatx4*)(er + n * 4);

  float acc[8] = {0.f, 0.f, 0.f, 0.f, 0.f, 0.f, 0.f, 0.f};
  float sm0 = 0.f, sm1 = 0.f, sm2 = 0.f, sm3 = 0.f;

  for (int c0 = 0; c0 < deg; c0 += 64) {
    const int cnt = min(deg - c0, 64);

    // ---- pass 1: lane-parallel edge metadata ----
    const int l = c0 + lane;
    const int idx = csrs[base + ((l < deg) ? l : (deg - 1))];
    const floatx4 el4 = *(const floatx4*)(el + (long)idx * 4);
    floatx4 w4;
#pragma unroll
    for (int j = 0; j < 4; ++j) {
      float e = el4[j] + er4[j];
      e = (e > 0.f) ? e : 0.2f * e;
      w4[j] = (l < deg) ? __expf(e) : 0.f;
    }
    sm0 += w4[0];
    sm1 += w4[1];
    sm2 += w4[2];
    sm3 += w4[3];
    *(floatx4*)(&w_s[wv][lane][0]) = w4;
    // same-wave LDS write->read: compiler inserts lgkmcnt wait, no barrier.

    // ---- pass 2: deep-pipelined gather, 8 rows in flight ----
    for (int i = 0; i < cnt; i += 8) {
      short8 hv[8];
#pragma unroll
      for (int u = 0; u < 8; ++u) {
        const int s = __builtin_amdgcn_readlane(idx, i + u);
        hv[u] = *(const short8*)(h + (long)s * HD + lane * 8);
      }
#pragma unroll
      for (int u = 0; u < 8; ++u) {
        const float w = w_s[wv][i + u][head];
#pragma unroll
        for (int j = 0; j < 8; ++j) acc[j] += w * b2f((u16)hv[u][j]);
      }
    }
  }

  // sm: butterfly-reduce the 4 per-head partial sums, then pick own head's.
#pragma unroll
  for (int m = 1; m < 64; m <<= 1) {
    sm0 += __shfl_xor(sm0, m, 64);
    sm1 += __shfl_xor(sm1, m, 64);
    sm2 += __shfl_xor(sm2, m, 64);
    sm3 += __shfl_xor(sm3, m, 64);
  }
  const float sm = (head == 0) ? sm0 : (head == 1) ? sm1 : (head == 2) ? sm2 : sm3;

  const float inv = 1.f / sm;
#pragma unroll
  for (int j = 0; j < 8; ++j) acc[j] = fmaxf(acc[j] * inv, 0.f);  // norm + relu

  if (MODE == 0) {
    u16 ub[8];
#pragma unroll
    for (int j = 0; j < 8; ++j) ub[j] = f2b(acc[j]);
    *(short8*)(ob + (long)n * HD + lane * 8) = *(short8*)ub;
  } else {
    // mean over heads: reduce across lane bits 4,5 (head index)
#pragma unroll
    for (int j = 0; j < 8; ++j) acc[j] += __shfl_xor(acc[j], 16, 64);
#pragma unroll
    for (int j = 0; j < 8; ++j) acc[j] += __shfl_xor(acc[j], 32, 64);
    if (lane < 16) {
      floatx4 o0, o1;
#pragma unroll
      for (int j = 0; j < 4; ++j) o0[j] = acc[j] * 0.25f;
#pragma unroll
      for (int j = 0; j < 4; ++j) o1[j] = acc[4 + j] * 0.25f;
      __builtin_nontemporal_store(o0, (floatx4*)(of + (long)n * DD + lane * 8));
      __builtin_nontemporal_store(o1, (floatx4*)(of + (long)n * DD + lane * 8 + 4));
    }
  }
}

extern "C" void kernel_launch(void* const* d_in, const int* in_sizes, int n_in,
                              void* d_out, int out_size, void* d_ws, size_t ws_size,
                              hipStream_t stream) {
  const float* x = (const float*)d_in[0];
  const int* src = (const int*)d_in[1];
  const int* dst = (const int*)d_in[2];
  const float* W0 = (const float*)d_in[3];
  const float* al0 = (const float*)d_in[4];
  const float* ar0 = (const float*)d_in[5];
  const float* W1 = (const float*)d_in[6];
  const float* al1 = (const float*)d_in[7];
  const float* ar1 = (const float*)d_in[8];
  float* out = (float*)d_out;

  char* p = (char*)d_ws;
  u16* h = (u16*)p;        p += (size_t)NN * HD * 2;   // 51.2 MB (bf16)
  u16* rst0 = (u16*)p;     p += (size_t)NN * HD * 2;   // 51.2 MB
  float* el = (float*)p;   p += (size_t)NN * 4 * 4;
  float* er = (float*)p;   p += (size_t)NN * 4 * 4;
  u16* Wt0 = (u16*)p;      p += 512 * 256 * 2;
  u16* Wt1 = (u16*)p;      p += 512 * 512 * 2;
  int* counts = (int*)p;   p += (size_t)NN * 4;
  int* cursor = (int*)p;   p += (size_t)NN * 4;
  int* rowp = (int*)p;     p += (size_t)(NN + 1) * 4;
  int* bsums = (int*)p;    p += 256 * 4;
  int* boffs = (int*)p;    p += 256 * 4;
  int* csrs = (int*)p;     p += (size_t)NE * 4;

  zero_k<<<NB, 256, 0, stream>>>(counts, NN);
  count_k<<<(NE + 255) / 256, 256, 0, stream>>>(dst, counts);
  blockscan_k<<<NB, 256, 0, stream>>>(counts, rowp, bsums);
  bscan_k<<<1, 256, 0, stream>>>(bsums, boffs);
  addoff_k<<<NB, 256, 0, stream>>>(rowp, cursor, boffs);
  scatter_k<<<(NE + 255) / 256, 256, 0, stream>>>(src, dst, cursor, csrs);
  transpose_k<<<(256 * 512 + 255) / 256, 256, 0, stream>>>(W0, Wt0, 256);
  transpose_k<<<(512 * 512 + 255) / 256, 256, 0, stream>>>(W1, Wt1, 512);

  const int gblocks = (NN + 63) / 64;  // 782
  gemm_el_er<256, true><<<gblocks, 512, 0, stream>>>(x, Wt0, al0, ar0, h, el, er);
  aggregate<0><<<(NN + 3) / 4, 256, 0, stream>>>(h, el, er, rowp, csrs, rst0, nullptr);
  gemm_el_er<512, false><<<gblocks, 512, 0, stream>>>(rst0, Wt1, al1, ar1, h, el, er);
  aggregate<1><<<(NN + 3) / 4, 256, 0, stream>>>(h, el, er, rowp, csrs, nullptr, out);
}